// Round 8
// baseline (691.455 us; speedup 1.0000x reference)
//
#include <hip/hip_runtime.h>

// UnPooling: x[32,112,112,64] f32 -> out[32,224,224,64] f32,
// out[:, ::2, ::2, :] = x, rest zero.
//
// Round 8: eliminate duplicate zero coverage while keeping the
// empirically-superior memset-first structure (memset variants beat all
// our-kernel-only variants 3/3, even with MORE total traffic):
//
//  1) hipMemset2DAsync zeroes exactly the 3584 ODD output rows
//     (57344 B contiguous each, pitch 114688 B, 206 MB total) on the
//     rocclr fill path. Bounds: 57344 + 3583*114688 + 57344
//     = 411,041,792 = out_size exactly.
//  2) expand_even_full (unchanged from R7, passed): writes each even
//     output row fully (data + interleaved zero pixels) from the input
//     row. 103 MB read + 206 MB write, contiguous 1 KiB wave stores,
//     bit4 lane-aliasing loads, cndmask zero select.
//
// Traffic: 206 (memset2D) + 103 (read) + 206 (expand) = 515 MB with no
// byte written twice — the minimum for this structure family.
// vs R7: -205 MB of memset coverage -> predicted ~-40 us.
typedef float f4 __attribute__((ext_vector_type(4)));

__global__ __launch_bounds__(256) void expand_even_full(
    const f4* __restrict__ x, f4* __restrict__ out) {
    const int tid = threadIdx.x;
    const int lo  = ((tid >> 5) << 4) | (tid & 15);  // [0,128) src f4 slot
    const bool is_data = (tid & 16) == 0;
    const f4 z = (f4){0.f, 0.f, 0.f, 0.f};

    // 3584 input rows, 1792 blocks -> 2 rows per block, grid-stride.
    for (int r = blockIdx.x; r < 3584; r += 1792) {
        const f4* __restrict__ xrow = x + (size_t)r * 1792;
        f4* __restrict__ orow = out + (size_t)(2 * r) * 3584;

        f4 v[14];
#pragma unroll
        for (int c = 0; c < 14; ++c) {
            v[c] = xrow[128 * c + lo];
        }
#pragma unroll
        for (int c = 0; c < 14; ++c) {
            __builtin_nontemporal_store(is_data ? v[c] : z,
                                        &orow[256 * c + tid]);
        }
    }
}

extern "C" void kernel_launch(void* const* d_in, const int* in_sizes, int n_in,
                              void* d_out, int out_size, void* d_ws, size_t ws_size,
                              hipStream_t stream) {
    // Zero exactly the odd rows via pitched 2D memset (rocclr fill path).
    // Row = 224*64*4 = 57344 B; odd rows start at +57344, stride 2 rows.
    char* base = (char*)d_out;
    hipMemset2DAsync(base + 57344, (size_t)114688, 0, (size_t)57344,
                     (size_t)3584, stream);

    // Even rows: full coverage (data + interleaved zeros), contiguous
    // wave stores.
    expand_even_full<<<dim3(1792), dim3(256), 0, stream>>>(
        (const f4*)d_in[0], (f4*)d_out);
}

// Round 9
// 432.273 us; speedup vs baseline: 1.5996x; 1.5996x over previous
//
#include <hip/hip_runtime.h>

// UnPooling: x[32,112,112,64] f32 -> out[32,224,224,64] f32,
// out[:, ::2, ::2, :] = x, rest zero.
//
// Round 9: R1 structure (best: 423 us) with ONE variable changed —
// scatter occupancy. The rocclr 1D fill sustains 6.3 TB/s at
// OccupancyPercent ~10 (~1k waves, long sequential runs per wave);
// every kernel we've written ran at full occupancy (64k+ interleaved
// write streams) and capped at 2.1-3.2 TB/s. Hypothesis: too many
// concurrent streams thrash HBM row buffers; fewer, longer streams
// restore fill-like BW.
//
//  1) hipMemsetAsync: all 411 MB of out (zeros), 1D fill path, ~65 us.
//  2) unpool_scatter_lowocc: 256 blocks x 256 threads (~1024 waves,
//     ~4 waves/CU, matching the fill's concurrency). Block b streams 14
//     CONSECUTIVE input rows [14b, 14b+14) -> one contiguous 1.6 MB
//     output region per block. Address math identical to R1/R3 (passed):
//       input f4 j = 16w + c4 -> even-row output f4 o = 32w + c4
//                  = ((j & ~15) << 1) | (j & 15)
//     nt stores (R1 A/B winner), plain cached loads; all 7 row-loads
//     issued before any store.
typedef float f4 __attribute__((ext_vector_type(4)));

__global__ __launch_bounds__(256) void unpool_scatter_lowocc(
    const f4* __restrict__ x, f4* __restrict__ out) {
    const int tid = threadIdx.x;
    const int r0  = blockIdx.x * 14;  // first of 14 consecutive rows

    for (int i = 0; i < 14; ++i) {
        const int r = r0 + i;
        const f4* __restrict__ xrow = x + (size_t)r * 1792;
        f4* __restrict__ orow = out + (size_t)(2 * r) * 3584;

        f4 v[7];
#pragma unroll
        for (int k = 0; k < 7; ++k) {
            v[k] = xrow[k * 256 + tid];
        }
#pragma unroll
        for (int k = 0; k < 7; ++k) {
            const int j = k * 256 + tid;
            const int o = ((j & ~15) << 1) | (j & 15);
            __builtin_nontemporal_store(v[k], &orow[o]);
        }
    }
}

extern "C" void kernel_launch(void* const* d_in, const int* in_sizes, int n_in,
                              void* d_out, int out_size, void* d_ws, size_t ws_size,
                              hipStream_t stream) {
    // Bulk zeros via the proven 1D fill path (NOT the slow 2D variant).
    hipMemsetAsync(d_out, 0, (size_t)out_size, stream);

    // Data scatter at fill-like occupancy: 256 blocks, 14 rows each.
    unpool_scatter_lowocc<<<dim3(256), dim3(256), 0, stream>>>(
        (const f4*)d_in[0], (f4*)d_out);
}